// Round 12
// baseline (537.450 us; speedup 1.0000x reference)
//
#include <hip/hip_runtime.h>
#include <hip/hip_bf16.h>

#define NNA 50000
#define NNB 50000
#define NE  800000
#define HD  256
#define EMBD 128
#define NDST (NNA + NNB)

#define BSH 9
#define NBK ((NDST + 511) >> 9)       // 196 buckets of 512 dsts
#define CAP 12288                      // bucket region capacity (mean 8192, +45 sigma)
#define PART_CHUNK 4096
#define PART_BLOCKS ((2 * NE + PART_CHUNK - 1) / PART_CHUNK)  // 391

#define CONV_BLOCKS 2048
#define KTOT 1024
#define PREP_IDS (2 * 2 * KTOT * 256 + 1024 + 32768)
#define PREP_BLOCKS ((PREP_IDS + 255) / 256)

typedef __attribute__((ext_vector_type(4))) int            i32x4;
typedef __attribute__((ext_vector_type(4))) float          f32x4;
typedef __attribute__((ext_vector_type(8))) short          bf16x8;
typedef __attribute__((ext_vector_type(4))) unsigned short u16x4;
typedef __attribute__((ext_vector_type(8))) unsigned short u16x8;

static __device__ __forceinline__ float bf2f(unsigned short u) {
  union { unsigned int i; float f; } v; v.i = ((unsigned int)u) << 16; return v.f;
}
static __device__ __forceinline__ unsigned short f2bf(float f) {
  __hip_bfloat16 h = __float2bfloat16(f);   // RTN-even, matches ml_dtypes
  return *reinterpret_cast<unsigned short*>(&h);
}

static __device__ __forceinline__ void gload_lds16(const void* g, void* l) {
  __builtin_amdgcn_global_load_lds((const __attribute__((address_space(1))) void*)g,
                                   (__attribute__((address_space(3))) void*)l, 16, 0, 0);
}

// ---------------- fused front kernel: convert | prep ----------------
// WcatT[l][t][n][k] bf16, K=1024: k/256 selects {Wl_rn, Wr_rn, Wl_rs, Wr_rs},
// each rounded to bf16 SEPARATELY (matches ref's per-matrix rounding).
__global__ __launch_bounds__(256)
void k_front(const float* __restrict__ xa, const float* __restrict__ xb,
             unsigned short* __restrict__ xout,
             const float* __restrict__ Wl, const float* __restrict__ Wr,
             const float* __restrict__ bl, const float* __restrict__ linW,
             unsigned short* __restrict__ WcatT, float* __restrict__ bias,
             unsigned short* __restrict__ linWT) {
  int b = blockIdx.x;
  if (b < CONV_BLOCKS) {
    const int n4a = NNA * HD / 4;
    const int n4  = (NNA + NNB) * HD / 4;
    int i = b * 256 + threadIdx.x;
    const int stride = CONV_BLOCKS * 256;
    for (; i < n4; i += stride) {
      const float* src = (i < n4a) ? (xa + (size_t)i * 4) : (xb + (size_t)(i - n4a) * 4);
      f32x4 v = *reinterpret_cast<const f32x4*>(src);
      u16x4 o;
      o[0] = f2bf(v[0]); o[1] = f2bf(v[1]); o[2] = f2bf(v[2]); o[3] = f2bf(v[3]);
      reinterpret_cast<u16x4*>(xout)[i] = o;
    }
    return;
  }
  b -= CONV_BLOCKS;
  {
    int id = b * 256 + threadIdx.x;
    if (id < 2 * 2 * KTOT * 256) {
      int n = id & 255;
      int k = (id >> 8) & (KTOT - 1);
      int t = (id >> 18) & 1;
      int l = id >> 19;
      int rn = (t == 0) ? 1 : 0;
      int rs = (t == 0) ? 2 : 3;
      int seg = k >> 8;          // 0:Wl_rn 1:Wr_rn 2:Wl_rs 3:Wr_rs
      int kk = k & 255;
      float v;
      if (seg == 0)      v = Wl[((l * 4 + rn) * HD + kk) * HD + n];
      else if (seg == 1) v = Wr[((l * 4 + rn) * HD + kk) * HD + n];
      else if (seg == 2) v = Wl[((l * 4 + rs) * HD + kk) * HD + n];
      else               v = Wr[((l * 4 + rs) * HD + kk) * HD + n];
      WcatT[((size_t)(l * 2 + t) * HD + n) * KTOT + k] = f2bf(v);
      return;
    }
    int id1 = id - 2 * 2 * KTOT * 256;
    if (id1 < 2 * 2 * 256) {
      int n = id1 & 255; int t = (id1 >> 8) & 1; int l = id1 >> 9;
      int rn = (t == 0) ? 1 : 0;
      int rs = (t == 0) ? 2 : 3;
      bias[id1] = bl[(l * 4 + rn) * HD + n] + bl[(l * 4 + rs) * HD + n];
      return;
    }
    int id2 = id1 - 2 * 2 * 256;
    if (id2 < EMBD * HD) {
      int k = id2 & 255; int n = id2 >> 8;
      linWT[n * HD + k] = f2bf(linW[k * EMBD + n]);
    }
  }
}

// ---------------- partition edges into fixed-capacity bucket regions ----------------
// payload u64: [dlocal:9]<<37 | [edge_idx:21]<<16 | [src:16]
__global__ __launch_bounds__(256)
void k_part(const int* __restrict__ e_ba, const int* __restrict__ e_ab,
            unsigned* __restrict__ tail, unsigned long long* __restrict__ csr_tmp) {
  __shared__ unsigned bh[NBK];
  __shared__ unsigned gbase[NBK];
  __shared__ unsigned lpos[NBK];
  const int tid = threadIdx.x;
  const int ebase = blockIdx.x * PART_CHUNK;
  int nvalid = 2 * NE - ebase;
  if (nvalid > PART_CHUNK) nvalid = PART_CHUNK;

  for (int i = tid; i < NBK; i += 256) { bh[i] = 0; lpos[i] = 0; }
  __syncthreads();

  unsigned sv[16], gv[16];
#pragma unroll
  for (int q = 0; q < 16; ++q) {
    int i = q * 256 + tid;
    int e = ebase + i;
    unsigned s = 0, g = 0;
    if (i < nvalid) {
      if (e < NE) { s = (unsigned)e_ba[e]; g = (unsigned)e_ba[NE + e]; }
      else { int f = e - NE; s = (unsigned)e_ab[f]; g = (unsigned)(NNA + e_ab[NE + f]); }
      atomicAdd(&bh[g >> BSH], 1u);
    }
    sv[q] = s; gv[q] = g;
  }
  __syncthreads();

  for (int i = tid; i < NBK; i += 256)
    if (bh[i]) gbase[i] = atomicAdd(&tail[i], bh[i]);
  __syncthreads();

#pragma unroll
  for (int q = 0; q < 16; ++q) {
    int i = q * 256 + tid;
    if (i < nvalid) {
      unsigned g = gv[q];
      unsigned bk = g >> BSH;
      unsigned e = (unsigned)(ebase + i);
      unsigned p = atomicAdd(&lpos[bk], 1u);
      unsigned long long v = ((unsigned long long)(g & 511u) << 37)
                           | ((unsigned long long)e << 16)
                           | (unsigned long long)sv[q];
      csr_tmp[(size_t)bk * CAP + gbase[bk] + p] = v;
    }
  }
}

// ---------------- per-bucket fill of the u64 slot table ----------------
__global__ __launch_bounds__(256)
void k_bfill(const unsigned* __restrict__ tail, const unsigned long long* __restrict__ csr_tmp,
             unsigned long long* __restrict__ slots64, int* __restrict__ cnt) {
  const int b = blockIdx.x;
  const int tid = threadIdx.x;
  unsigned nb = tail[b];
  if (nb > CAP) nb = CAP;
  const int d0 = b << BSH;
  const unsigned long long* src = csr_tmp + (size_t)b * CAP;

  __shared__ unsigned lpos[512];
  lpos[tid] = 0; lpos[tid + 256] = 0;
  __syncthreads();

  for (unsigned i = tid; i < nb; i += 256) {
    unsigned long long v = src[i];
    unsigned dl = (unsigned)(v >> 37);
    unsigned p = atomicAdd(&lpos[dl], 1u);
    if (p < 64) slots64[((size_t)(d0 + dl) << 6) + p] = v & 0x1FFFFFFFFFFULL;
  }
  __syncthreads();

  int da = d0 + tid, db = d0 + tid + 256;
  if (da < NDST) cnt[da] = (int)lpos[tid];
  if (db < NDST) cnt[db] = (int)lpos[tid + 256];
}

// ---------------- per-dst 64-lane bitonic sort by edge index (determinism) ----------------
__global__ __launch_bounds__(256)
void k_sort(const unsigned long long* __restrict__ slots64, const int* __restrict__ cnt,
            unsigned short* __restrict__ slots16) {
  int w = blockIdx.x * 4 + (threadIdx.x >> 6);
  int lane = threadIdx.x & 63;
  int deg = cnt[w];
  int m = deg < 64 ? deg : 64;
  unsigned long long key = (lane < m) ? slots64[((size_t)w << 6) + lane] : ~0ULL;

#pragma unroll
  for (int k = 2; k <= 64; k <<= 1) {
#pragma unroll
    for (int j = k >> 1; j >= 1; j >>= 1) {
      unsigned long long other = __shfl_xor(key, j);
      bool up = ((lane & k) == 0);
      bool lower = ((lane & j) == 0);
      bool keep_min = (lower == up);
      bool swap = keep_min ? (other < key) : (other > key);
      if (swap) key = other;
    }
  }
  slots16[((size_t)w << 6) + lane] = (unsigned short)(key & 0xFFFFULL);
}

// ---------------- atomic-free mean aggregation (slot table, both types fused) ----------------
__global__ __launch_bounds__(256)
void k_aggregate(const unsigned short* __restrict__ xa,
                 const unsigned short* __restrict__ xb,
                 const unsigned short* __restrict__ slots,
                 const int* __restrict__ cnt,
                 unsigned short* __restrict__ mean_a, unsigned short* __restrict__ mean_b) {
  int w = blockIdx.x * 4 + (threadIdx.x >> 6);
  int lane = threadIdx.x & 63;
  const unsigned short* xsrc;
  unsigned short* outp;
  int deg = cnt[w];
  if (w < NNA) {
    xsrc = xb;
    outp = mean_a + (size_t)w * HD;
  } else {
    xsrc = xa;
    outp = mean_b + (size_t)(w - NNA) * HD;
  }
  int m = deg < 64 ? deg : 64;
  int s_all = (int)slots[(size_t)w * 64 + lane];
  const int half = lane >> 5;
  const int l31 = lane & 31;

  float acc[8];
#pragma unroll
  for (int k = 0; k < 8; ++k) acc[k] = 0.f;

  int j = 0;
  for (; j + 8 <= m; j += 8) {
    int sj[4];
#pragma unroll
    for (int i = 0; i < 4; ++i) sj[i] = __shfl(s_all, j + 2 * i + half);
    u16x8 v[4];
#pragma unroll
    for (int i = 0; i < 4; ++i)
      v[i] = *reinterpret_cast<const u16x8*>(xsrc + (size_t)sj[i] * HD + l31 * 8);
#pragma unroll
    for (int i = 0; i < 4; ++i)
#pragma unroll
      for (int k = 0; k < 8; ++k) acc[k] += bf2f(v[i][k]);
  }
  for (; j + 2 <= m; j += 2) {
    int sj = __shfl(s_all, j + half);
    u16x8 v = *reinterpret_cast<const u16x8*>(xsrc + (size_t)sj * HD + l31 * 8);
#pragma unroll
    for (int k = 0; k < 8; ++k) acc[k] += bf2f(v[k]);
  }
  if (j < m && half == 0) {
    int sj = __shfl(s_all, j);
    u16x8 v = *reinterpret_cast<const u16x8*>(xsrc + (size_t)sj * HD + l31 * 8);
#pragma unroll
    for (int k = 0; k < 8; ++k) acc[k] += bf2f(v[k]);
  }

#pragma unroll
  for (int k = 0; k < 8; ++k) acc[k] += __shfl_xor(acc[k], 32);

  float inv = deg > 0 ? 1.0f / (float)deg : 0.0f;
  if (half == 0) {
    u16x8 o;
#pragma unroll
    for (int k = 0; k < 8; ++k) o[k] = f2bf(acc[k] * inv);
    *reinterpret_cast<u16x8*>(outp + l31 * 8) = o;
  }
}

// ---------------- fused bf16 MFMA GEMM, global_load_lds + double buffer ----------------
// A(K) = [mean(0:256) | x(256:512) | x(512:768) | x(768:1024)] via Klo boundary:
// kglob < Klo -> Alo at kbase=kglob; else Ahi at kbase = kglob & 255.
template <bool RELU, bool OUTF32>
__global__ __launch_bounds__(256)
void k_gemm(const unsigned short* __restrict__ Alo,
            const unsigned short* __restrict__ Ahi,
            const unsigned short* __restrict__ BT,
            const float* __restrict__ bias,
            void* __restrict__ Cout,
            int M, int N, int Ktot, int Klo,
            long long sA, long long sB, long long sBias, long long sCbytes) {
  const int z = blockIdx.z;
  Alo += (long long)z * sA;
  Ahi += (long long)z * sA;
  BT += (long long)z * sB;
  bias += (long long)z * sBias;
  Cout = (void*)((char*)Cout + (long long)z * sCbytes);

  __shared__ char smem[65536];
  const int t = threadIdx.x;
  const int bm = blockIdx.x, bn = blockIdx.y;
  const int lane = t & 63, wid = t >> 6;
  const int wm = wid >> 1, wn = wid & 1;
  const int l15 = lane & 15, l4 = lane >> 4;
  const int rgrp = lane >> 3;
  const int boff = (((lane & 7) ^ rgrp) << 4);

  f32x4 acc[4][4];
#pragma unroll
  for (int i = 0; i < 4; ++i)
#pragma unroll
    for (int j = 0; j < 4; ++j) acc[i][j] = (f32x4){0.f, 0.f, 0.f, 0.f};

  const int nks = Ktot >> 6;

  auto stage = [&](int ks, int buf) {
    const int kglob = ks << 6;
    const unsigned short* Asrc = (kglob < Klo) ? Alo : Ahi;
    const int kbase = (kglob < Klo) ? kglob : (kglob & 255);
    char* sA_ = smem + buf * 16384;
    char* sB_ = smem + 32768 + buf * 16384;
#pragma unroll
    for (int i = 0; i < 4; ++i) {
      int rloc = wid * 32 + i * 8;
      int rA = bm * 128 + rloc + rgrp;
      if (rA >= M) rA = M - 1;
      const char* ga = (const char*)(Asrc + (size_t)rA * HD + kbase) + boff;
      gload_lds16(ga, sA_ + rloc * 128);
      int rB = bn * 128 + rloc + rgrp;
      const char* gb = (const char*)(BT + (size_t)rB * Ktot + kglob) + boff;
      gload_lds16(gb, sB_ + rloc * 128);
    }
  };

  stage(0, 0);
  __syncthreads();

  for (int ks = 0; ks < nks; ++ks) {
    if (ks + 1 < nks) stage(ks + 1, (ks + 1) & 1);
    const char* sA_ = smem + (ks & 1) * 16384;
    const char* sB_ = smem + 32768 + (ks & 1) * 16384;
#pragma unroll
    for (int kk = 0; kk < 2; ++kk) {
      bf16x8 af[4], bfr[4];
#pragma unroll
      for (int f = 0; f < 4; ++f) {
        int r = wm * 64 + f * 16 + l15;
        af[f] = *reinterpret_cast<const bf16x8*>(
            sA_ + r * 128 + ((kk * 64 + l4 * 16) ^ ((r & 7) << 4)));
        int n = wn * 64 + f * 16 + l15;
        bfr[f] = *reinterpret_cast<const bf16x8*>(
            sB_ + n * 128 + ((kk * 64 + l4 * 16) ^ ((n & 7) << 4)));
      }
#pragma unroll
      for (int fm = 0; fm < 4; ++fm)
#pragma unroll
        for (int fn = 0; fn < 4; ++fn)
          acc[fm][fn] = __builtin_amdgcn_mfma_f32_16x16x32_bf16(af[fm], bfr[fn], acc[fm][fn], 0, 0, 0);
    }
    __syncthreads();
  }

#pragma unroll
  for (int fm = 0; fm < 4; ++fm) {
    int row0 = bm * 128 + wm * 64 + fm * 16 + l4 * 4;
#pragma unroll
    for (int fn = 0; fn < 4; ++fn) {
      int col = bn * 128 + wn * 64 + fn * 16 + l15;
      float bv = bias[col];
      f32x4 d = acc[fm][fn];
#pragma unroll
      for (int r = 0; r < 4; ++r) {
        int rg = row0 + r;
        if (rg < M) {
          float v = d[r] + bv;
          if (RELU) v = v > 0.f ? v : 0.f;
          if (OUTF32)
            reinterpret_cast<float*>(Cout)[(size_t)rg * N + col] = v;
          else
            reinterpret_cast<unsigned short*>(Cout)[(size_t)rg * N + col] = f2bf(v);
        }
      }
    }
  }
}

// ---------------- launch ----------------

extern "C" void kernel_launch(void* const* d_in, const int* in_sizes, int n_in,
                              void* d_out, int out_size, void* d_ws, size_t ws_size,
                              hipStream_t stream) {
  const float* x_a  = (const float*)d_in[0];
  const float* x_b  = (const float*)d_in[1];
  const int*   e_ab = (const int*)d_in[2];
  const int*   e_ba = (const int*)d_in[3];
  const float* Wl   = (const float*)d_in[4];
  const float* bl   = (const float*)d_in[5];
  const float* Wr   = (const float*)d_in[6];
  const float* linW = (const float*)d_in[7];
  const float* linb = (const float*)d_in[8];
  float* out = (float*)d_out;

  char* ws = (char*)d_ws;
  size_t off = 0;
  auto alloc = [&](size_t bytes) {
    char* p = ws + off;
    off += (bytes + 255) & ~(size_t)255;
    return p;
  };
  unsigned short* x0   = (unsigned short*)alloc((size_t)2 * NNA * HD * 2);
  unsigned short* x1   = (unsigned short*)alloc((size_t)2 * NNA * HD * 2);
  unsigned short* mean = (unsigned short*)alloc((size_t)2 * NNA * HD * 2);
  int*            cnt  = (int*)alloc((size_t)NDST * 4);
  unsigned long long* slots64 = (unsigned long long*)alloc((size_t)NDST * 64 * 8);
  unsigned short* slots16 = (unsigned short*)alloc((size_t)NDST * 64 * 2);
  unsigned*       tail = (unsigned*)alloc((size_t)NBK * 4);        // memset to 0
  unsigned long long* csr_tmp = (unsigned long long*)alloc((size_t)NBK * CAP * 8);
  unsigned short* wcatT  = (unsigned short*)alloc((size_t)2 * 2 * 256 * KTOT * 2);
  float*          biasv  = (float*)alloc((size_t)2 * 2 * 256 * 4);
  unsigned short* linWT  = (unsigned short*)alloc((size_t)EMBD * HD * 2);
  (void)ws_size; (void)in_sizes; (void)n_in; (void)out_size;

  hipMemsetAsync(tail, 0, (size_t)NBK * 4, stream);

  k_front<<<CONV_BLOCKS + PREP_BLOCKS, 256, 0, stream>>>(
      x_a, x_b, x0, Wl, Wr, bl, linW, wcatT, biasv, linWT);
  k_part<<<PART_BLOCKS, 256, 0, stream>>>(e_ba, e_ab, tail, csr_tmp);
  k_bfill<<<NBK, 256, 0, stream>>>(tail, csr_tmp, slots64, cnt);
  k_sort<<<NDST / 4, 256, 0, stream>>>(slots64, cnt, slots16);

  unsigned short* xcur = x0;
  unsigned short* xnxt = x1;

  for (int l = 0; l < 2; ++l) {
    k_aggregate<<<(NNA + NNB) / 4, 256, 0, stream>>>(
        xcur, xcur + (size_t)NNA * HD, slots16, cnt,
        mean, mean + (size_t)NNA * HD);
    dim3 g((NNA + 127) / 128, 2, 2);
    k_gemm<true, false><<<g, 256, 0, stream>>>(
        mean, xcur, wcatT + (size_t)l * 2 * 256 * KTOT, biasv + l * 2 * 256, xnxt,
        NNA, 256, KTOT, 256,
        (long long)NNA * HD, (long long)256 * KTOT, 256, (long long)NNA * HD * 2);
    unsigned short* tmp = xcur; xcur = xnxt; xnxt = tmp;
  }

  dim3 gf((NNA + 127) / 128, 1, 2);
  k_gemm<false, true><<<gf, 256, 0, stream>>>(
      xcur, xcur, linWT, linb, out,
      NNA, EMBD, 256, 256,
      (long long)NNA * HD, 0, 0, (long long)NNA * EMBD * 4);
}